// Round 5
// baseline (1450.168 us; speedup 1.0000x reference)
//
#include <hip/hip_runtime.h>
#include <math.h>

typedef unsigned short u16;
typedef u16 u16x8 __attribute__((ext_vector_type(8)));
typedef __bf16 bf16x8 __attribute__((ext_vector_type(8)));
typedef float f32x4 __attribute__((ext_vector_type(4)));

#define MBL (1LL << 20)

__device__ __forceinline__ u16 f2bf(float x) {
    unsigned u = __float_as_uint(x);
    return (u16)((u + 0x7fffu + ((u >> 16) & 1u)) >> 16);
}
__device__ __forceinline__ float bf2f(u16 h) { return __uint_as_float(((unsigned)h) << 16); }
__device__ __forceinline__ float silu_f(float x) { return x / (1.f + __expf(-x)); }

#define GLDS(gp, off) __builtin_amdgcn_global_load_lds( \
    (const __attribute__((address_space(1))) void*)(gp), \
    (__attribute__((address_space(3))) void*)(&SL[off]), 16, 0, 0)

// ---------------------------------------------------------------------------
// Split-bf16 MFMA GEMM.  C = (A @ B^T) with split operands (hi+lo bf16),
// 3 MFMA per K-slice (hh+hl+lh).  B always pre-split (global_load_lds).
// SPLITA=1: A pre-split (global_load_lds); SPLITA=0: A fp32, in-reg split.
// EPI: 0 = fp32 store: c*alpha + bias (+addp)
//      1 = split store: c + bias
//      2 = silu(c + bias) split store
//      3 = exp(c*alpha) split store + fp32 rowsum atomicAdd
//      4 = c * (1/rsum[row]) split store
// z: bh = blockIdx.z; zb=bh>>1, zh=bh&1 strides (pure-z X -> sXb=2X, sXh2=X).
// ---------------------------------------------------------------------------
template<int SPLITA, int EPI>
__global__ __launch_bounds__(256)
void gemm_ss(const float* __restrict__ Af,
             const u16* __restrict__ Ah, const u16* __restrict__ Al,
             const u16* __restrict__ Bh, const u16* __restrict__ Bl,
             float* __restrict__ Cf, u16* __restrict__ Ch, u16* __restrict__ Cl,
             float* __restrict__ rsum,
             long lda, long ldb, long ldc, int K, float alpha,
             const float* __restrict__ bias,
             const float* __restrict__ addp, long ldadd,
             long sAb, long sAh2, long sBb, long sBh2, long sCb, long sCh2)
{
    const int z = blockIdx.z, zb = z >> 1, zh = z & 1;
    const long offA = (long)zb * sAb + (long)zh * sAh2;
    const long offB = (long)zb * sBb + (long)zh * sBh2;
    const long offC = (long)zb * sCb + (long)zh * sCh2;
    if (SPLITA) { Ah += offA; Al += offA; } else { Af += offA; }
    Bh += offB; Bl += offB;
    if (EPI == 0) Cf += offC; else { Ch += offC; Cl += offC; }
    if (EPI >= 3) rsum += (long)z * 2048;

    // LDS: 4 tiles [128][32] u16: AH, AL, BH, BL
    __shared__ u16 SL[16384];
    const int AH = 0, AL = 4096, BH = 8192, BL = 12288;

    const int tid = threadIdx.x;
    const int wave = tid >> 6, lane = tid & 63;
    const long m0 = (long)blockIdx.y * 128;
    const long n0 = (long)blockIdx.x * 128;

    // direct-load staging map: issue t (0,1): row = wave*16 + (lane>>2) + t*64,
    // kcol = (lane&3)*8; lds (u16) = tile + wave*512 + t*2048 (+ lane*8 by HW)
    const int lrow = lane >> 2;
    const int kcol = (lane & 3) << 3;
    const int ldsW = wave * 512;

    // fp32-A staging map (SPLITA=0)
    const int srow = tid >> 1;
    const int sh   = (tid & 1) << 4;
    const float* gA = SPLITA ? nullptr : (Af + (m0 + srow) * lda + sh);
    const int sB = srow * 32 + sh;

    const int wr = (wave >> 1) << 6;
    const int wc = (wave & 1) << 6;
    const int fr = lane & 15;
    const int fk = (lane >> 4) << 3;

    f32x4 acc[4][4];
#pragma unroll
    for (int i = 0; i < 4; ++i)
#pragma unroll
        for (int j = 0; j < 4; ++j) acc[i][j] = (f32x4)0.f;

    for (int kb = 0; kb < K; kb += 32) {
        float a[16];
        if (!SPLITA) {
            *(float4*)&a[0]  = *(const float4*)(gA + kb);
            *(float4*)&a[4]  = *(const float4*)(gA + kb + 4);
            *(float4*)&a[8]  = *(const float4*)(gA + kb + 8);
            *(float4*)&a[12] = *(const float4*)(gA + kb + 12);
        }
        __syncthreads();   // previous iteration's LDS reads complete
#pragma unroll
        for (int t = 0; t < 2; ++t) {
            const long row = wave * 16 + lrow + t * 64;
            GLDS(Bh + (n0 + row) * ldb + kb + kcol, BH + ldsW + t * 2048);
            GLDS(Bl + (n0 + row) * ldb + kb + kcol, BL + ldsW + t * 2048);
            if (SPLITA) {
                GLDS(Ah + (m0 + row) * lda + kb + kcol, AH + ldsW + t * 2048);
                GLDS(Al + (m0 + row) * lda + kb + kcol, AL + ldsW + t * 2048);
            }
        }
        if (!SPLITA) {
            u16 hv[16], lv[16];
#pragma unroll
            for (int u = 0; u < 16; ++u) {
                u16 h = f2bf(a[u]); hv[u] = h; lv[u] = f2bf(a[u] - bf2f(h));
            }
            *(u16x8*)&SL[AH + sB]     = *(u16x8*)&hv[0];
            *(u16x8*)&SL[AH + sB + 8] = *(u16x8*)&hv[8];
            *(u16x8*)&SL[AL + sB]     = *(u16x8*)&lv[0];
            *(u16x8*)&SL[AL + sB + 8] = *(u16x8*)&lv[8];
        }
        __syncthreads();   // drains vmcnt (compiler) + lgkm

        bf16x8 fah[4], fal[4], fbh[4], fbl[4];
#pragma unroll
        for (int i = 0; i < 4; ++i) {
            const int r = (wr + (i << 4) + fr) * 32 + fk;
            fah[i] = *(const bf16x8*)&SL[AH + r];
            fal[i] = *(const bf16x8*)&SL[AL + r];
        }
#pragma unroll
        for (int j = 0; j < 4; ++j) {
            const int r = (wc + (j << 4) + fr) * 32 + fk;
            fbh[j] = *(const bf16x8*)&SL[BH + r];
            fbl[j] = *(const bf16x8*)&SL[BL + r];
        }
#pragma unroll
        for (int i = 0; i < 4; ++i)
#pragma unroll
            for (int j = 0; j < 4; ++j) {
                acc[i][j] = __builtin_amdgcn_mfma_f32_16x16x32_bf16(fah[i], fbh[j], acc[i][j], 0, 0, 0);
                acc[i][j] = __builtin_amdgcn_mfma_f32_16x16x32_bf16(fah[i], fbl[j], acc[i][j], 0, 0, 0);
                acc[i][j] = __builtin_amdgcn_mfma_f32_16x16x32_bf16(fal[i], fbh[j], acc[i][j], 0, 0, 0);
            }
    }

    const int rl = (lane >> 4) << 2;
#pragma unroll
    for (int i = 0; i < 4; ++i) {
#pragma unroll
        for (int r2 = 0; r2 < 4; ++r2) {
            const long row = m0 + wr + (i << 4) + rl + r2;
            float psum = 0.f;
            float rinv = 0.f;
            if (EPI == 4) rinv = 1.f / rsum[row];
#pragma unroll
            for (int j = 0; j < 4; ++j) {
                const long col = n0 + wc + (j << 4) + fr;
                float c = acc[i][j][r2];
                if (EPI == 0 || EPI == 1 || EPI == 2) {
                    c = c * alpha + (bias ? bias[col] : 0.f);
                }
                if (EPI == 0) {
                    if (addp) c += addp[row * ldadd + col];
                    Cf[row * ldc + col] = c;
                } else if (EPI == 1 || EPI == 2) {
                    if (EPI == 2) c = silu_f(c);
                    u16 h = f2bf(c);
                    Ch[row * ldc + col] = h;
                    Cl[row * ldc + col] = f2bf(c - bf2f(h));
                } else if (EPI == 3) {
                    float p = __expf(c * alpha);
                    psum += p;
                    u16 h = f2bf(p);
                    Ch[row * ldc + col] = h;
                    Cl[row * ldc + col] = f2bf(p - bf2f(h));
                } else {   // EPI == 4
                    c *= rinv;
                    u16 h = f2bf(c);
                    Ch[row * ldc + col] = h;
                    Cl[row * ldc + col] = f2bf(c - bf2f(h));
                }
            }
            if (EPI == 3) {
                psum += __shfl_xor(psum, 1);
                psum += __shfl_xor(psum, 2);
                psum += __shfl_xor(psum, 4);
                psum += __shfl_xor(psum, 8);
                if ((lane & 15) == 0) atomicAdd(&rsum[row], psum);
            }
        }
    }
}

// elementwise split: fp32 -> bf16 hi + lo.  2048 elems per block.
__global__ __launch_bounds__(256)
void split_f32(const float* __restrict__ in, u16* __restrict__ hi, u16* __restrict__ lo)
{
    const long i = (((long)blockIdx.x << 8) + threadIdx.x) << 3;
    float4 v0 = *(const float4*)(in + i), v1 = *(const float4*)(in + i + 4);
    float f[8] = {v0.x, v0.y, v0.z, v0.w, v1.x, v1.y, v1.z, v1.w};
    u16x8 h8, l8;
#pragma unroll
    for (int u = 0; u < 8; ++u) { u16 h = f2bf(f[u]); h8[u] = h; l8[u] = f2bf(f[u] - bf2f(h)); }
    *(u16x8*)(hi + i) = h8;
    *(u16x8*)(lo + i) = l8;
}

// v fp32 [s=2048][1024] per batch -> vt split [d=512][s=2048] per (batch,head)
__global__ __launch_bounds__(256)
void transpose_vs(const float* __restrict__ v, u16* __restrict__ vth, u16* __restrict__ vtl,
                  long sVb, long sVh, long sTb, long sTh)
{
    const int z = blockIdx.z, s = z >> 1, h = z & 1;
    const float* src = v + (long)s * sVb + (long)h * sVh;
    u16* dh = vth + (long)s * sTb + (long)h * sTh;
    u16* dl = vtl + (long)s * sTb + (long)h * sTh;
    __shared__ float T[64][68];
    const int t = threadIdx.x;
    const int r = t >> 2, c0 = (t & 3) << 4;
    const long sBase = (long)blockIdx.x * 64;
    const long dBase = (long)blockIdx.y * 64;
    const float* sp = src + (sBase + r) * 1024 + dBase + c0;
#pragma unroll
    for (int q = 0; q < 4; ++q)
        *(float4*)&T[r][c0 + 4 * q] = *(const float4*)(sp + 4 * q);
    __syncthreads();
    u16x8 h8[2], l8[2];
#pragma unroll
    for (int g = 0; g < 2; ++g)
#pragma unroll
        for (int u = 0; u < 8; ++u) {
            float f = T[c0 + g * 8 + u][r];
            u16 h = f2bf(f);
            h8[g][u] = h; l8[g][u] = f2bf(f - bf2f(h));
        }
    const long o = (dBase + r) * 2048 + sBase + c0;
    *(u16x8*)&dh[o] = h8[0]; *(u16x8*)&dh[o + 8] = h8[1];
    *(u16x8*)&dl[o] = l8[0]; *(u16x8*)&dl[o + 8] = l8[1];
}

// LayerNorm rows of 512; 1 wave/row, 4 rows/block
__global__ __launch_bounds__(256)
void layernorm_rows(const float* __restrict__ h,
                    const float* __restrict__ gamma,
                    const float* __restrict__ beta,
                    float* __restrict__ o)
{
    const int lane = threadIdx.x & 63;
    const long row = ((long)blockIdx.x << 2) + (threadIdx.x >> 6);
    const float* hr = h + row * 512;
    float v[8];
    *(float4*)&v[0] = *(const float4*)(hr + (lane << 3));
    *(float4*)&v[4] = *(const float4*)(hr + (lane << 3) + 4);
    float s = 0.f;
#pragma unroll
    for (int i = 0; i < 8; ++i) s += v[i];
#pragma unroll
    for (int off = 32; off >= 1; off >>= 1) s += __shfl_xor(s, off);
    const float mu = s * (1.f / 512.f);
    float sq = 0.f;
#pragma unroll
    for (int i = 0; i < 8; ++i) { v[i] -= mu; sq = fmaf(v[i], v[i], sq); }
#pragma unroll
    for (int off = 32; off >= 1; off >>= 1) sq += __shfl_xor(sq, off);
    const float rs = rsqrtf(sq * (1.f / 512.f) + 1e-5f);
    float g[8], b[8];
    *(float4*)&g[0] = *(const float4*)(gamma + (lane << 3));
    *(float4*)&g[4] = *(const float4*)(gamma + (lane << 3) + 4);
    *(float4*)&b[0] = *(const float4*)(beta + (lane << 3));
    *(float4*)&b[4] = *(const float4*)(beta + (lane << 3) + 4);
    float ov[8];
#pragma unroll
    for (int i = 0; i < 8; ++i) ov[i] = fmaf(v[i] * rs, g[i], b[i]);
    float* orow = o + row * 512;
    *(float4*)(orow + (lane << 3))     = *(float4*)&ov[0];
    *(float4*)(orow + (lane << 3) + 4) = *(float4*)&ov[4];
}

extern "C" void kernel_launch(void* const* d_in, const int* in_sizes, int n_in,
                              void* d_out, int out_size, void* d_ws, size_t ws_size,
                              hipStream_t stream)
{
    const float* x    = (const float*)d_in[0];
    const float* skip = (const float*)d_in[1];
    const float* Wq   = (const float*)d_in[2];
    const float* bq   = (const float*)d_in[3];
    const float* Wk   = (const float*)d_in[4];
    const float* bk   = (const float*)d_in[5];
    const float* Wv   = (const float*)d_in[6];
    const float* bv   = (const float*)d_in[7];
    const float* Wo   = (const float*)d_in[8];
    const float* bo   = (const float*)d_in[9];
    const float* Wl   = (const float*)d_in[10];
    const float* bl   = (const float*)d_in[11];
    const float* gm   = (const float*)d_in[12];
    const float* bt   = (const float*)d_in[13];
    const float* Wp   = (const float*)d_in[14];
    const float* bp   = (const float*)d_in[15];
    float* out = (float*)d_out;

    char* W = (char*)d_ws;
    // weight splits (10 MB) + rsum at 10 MB; region 0..16 MB
    u16* wqh = (u16*)(W);
    u16* wql = wqh + 524288;
    u16* wkh = wql + 524288;  u16* wkl = wkh + 524288;
    u16* wvh = wkl + 524288;  u16* wvl = wvh + 524288;
    u16* woh = wvl + 524288;  u16* wol = woh + 524288;
    u16* wlh = wol + 524288;  u16* wll = wlh + 262144;
    u16* wph = wll + 262144;  u16* wpl = wph + 262144;
    float* rsum = (float*)(W + 10 * MBL);
    // attO split: 16..48 / 48..80 MB;  oproj split: 80..96 / 96..112 MB
    u16* ahi  = (u16*)(W + 16 * MBL);
    u16* alo  = (u16*)(W + 48 * MBL);
    u16* ophi = (u16*)(W + 80 * MBL);
    u16* oplo = (u16*)(W + 96 * MBL);
    float* hb  = (float*)(W + 16 * MBL);   // reuses attO-hi (dead after Wo)
    float* lnh = (float*)(W + 48 * MBL);   // reuses attO-lo
    char* PB = W + 112 * MBL;              // per-batch slots, 56 MB each

    long avail = (long)ws_size - 112 * MBL;
    long gbl = avail / (56 * MBL);
    int gb = gbl < 1 ? 1 : (gbl > 8 ? 8 : (int)gbl);

    const long SLOT_U = 29360128;   // 56 MB in u16
    const long SLOT_F = 14680064;   // 56 MB in fp32
    u16*   qh0 = (u16*)(PB);                      // +0  (hi 4MB, lo 4MB)
    u16*   kh0 = (u16*)(PB + 8 * MBL);
    u16*   vth0 = (u16*)(PB + 16 * MBL);          // per head: hi 2MB + lo 2MB
    u16*   ph0 = (u16*)(PB + 24 * MBL);           // P~ interleaved, 16MB/head
    float* vtm0 = (float*)(PB + 24 * MBL);        // v fp32 temp (dead before P~)

    const float sscale = 0.044194173824159216f;   // 1/sqrt(512)
    const long Z = 0;

    hipMemsetAsync(rsum, 0, 16 * 2048 * 4, stream);

    split_f32<<<256, 256, 0, stream>>>(Wq, wqh, wql);
    split_f32<<<256, 256, 0, stream>>>(Wk, wkh, wkl);
    split_f32<<<256, 256, 0, stream>>>(Wv, wvh, wvl);
    split_f32<<<256, 256, 0, stream>>>(Wo, woh, wol);
    split_f32<<<128, 256, 0, stream>>>(Wl, wlh, wll);
    split_f32<<<128, 256, 0, stream>>>(Wp, wph, wpl);

    for (int b0 = 0; b0 < 8; b0 += gb) {
        const int gc = (8 - b0) < gb ? (8 - b0) : gb;
        const float* xg = x + (long)b0 * 1048576;
        // ---- QKV: A = x (fp32, in-reg split), B = W split ----
        gemm_ss<0, 1><<<dim3(8, 16, gc), 256, 0, stream>>>(
            xg, nullptr, nullptr, wqh, wql, nullptr, qh0, qh0 + 2097152, nullptr,
            512, 512, 1024, 512, 1.f, bq, nullptr, 0,
            2097152L, 1048576L, Z, Z, 2 * SLOT_U, SLOT_U);
        gemm_ss<0, 1><<<dim3(8, 16, gc), 256, 0, stream>>>(
            xg, nullptr, nullptr, wkh, wkl, nullptr, kh0, kh0 + 2097152, nullptr,
            512, 512, 1024, 512, 1.f, bk, nullptr, 0,
            2097152L, 1048576L, Z, Z, 2 * SLOT_U, SLOT_U);
        gemm_ss<0, 0><<<dim3(8, 16, gc), 256, 0, stream>>>(
            xg, nullptr, nullptr, wvh, wvl, vtm0, nullptr, nullptr, nullptr,
            512, 512, 1024, 512, 1.f, bv, nullptr, 0,
            2097152L, 1048576L, Z, Z, 2 * SLOT_F, SLOT_F);
        // ---- v -> vt split ----
        transpose_vs<<<dim3(32, 8, 2 * gc), 256, 0, stream>>>(
            vtm0, vth0, vth0 + 1048576,
            SLOT_F, 512, SLOT_U, 2097152L);
        // ---- scores: P~ = exp(q@k^T / sqrt(512)), rowsums ----
        gemm_ss<1, 3><<<dim3(16, 16, 2 * gc), 256, 0, stream>>>(
            nullptr, qh0, qh0 + 2097152, kh0, kh0 + 2097152,
            nullptr, ph0, ph0 + 2048, rsum + (long)b0 * 4096,
            1024, 1024, 4096, 512, sscale, nullptr, nullptr, 0,
            SLOT_U, 512, SLOT_U, 512, SLOT_U, 8388608L);
        // ---- attO = (P~ @ vt^T) / rowsum ----
        gemm_ss<1, 4><<<dim3(4, 16, 2 * gc), 256, 0, stream>>>(
            nullptr, ph0, ph0 + 2048, vth0, vth0 + 1048576,
            nullptr, ahi + (long)b0 * 2097152, alo + (long)b0 * 2097152,
            rsum + (long)b0 * 4096,
            4096, 2048, 1024, 2048, 1.f, nullptr, nullptr, 0,
            SLOT_U, 8388608L, SLOT_U, 2097152L, 2097152L, 512);
    }

    // ---- oproj = silu(attO @ Wo^T + bo), split ----
    gemm_ss<1, 2><<<dim3(4, 128, 1), 256, 0, stream>>>(
        nullptr, ahi, alo, woh, wol, nullptr, ophi, oplo, nullptr,
        1024, 1024, 512, 1024, 1.f, bo, nullptr, 0, Z, Z, Z, Z, Z, Z);
    // ---- hb = oproj @ Wl^T + bl (fp32) ----
    gemm_ss<1, 0><<<dim3(4, 128, 1), 256, 0, stream>>>(
        nullptr, ophi, oplo, wlh, wll, hb, nullptr, nullptr, nullptr,
        512, 512, 512, 512, 1.f, bl, nullptr, 0, Z, Z, Z, Z, Z, Z);
    // ---- LayerNorm ----
    layernorm_rows<<<4096, 256, 0, stream>>>(hb, gm, bt, lnh);
    // ---- out = lnh + skip @ Wp^T + bp ----
    gemm_ss<0, 0><<<dim3(4, 128, 1), 256, 0, stream>>>(
        skip, nullptr, nullptr, wph, wpl, out, nullptr, nullptr, nullptr,
        512, 512, 512, 512, 1.f, bp, lnh, 512, Z, Z, Z, Z, Z, Z);
}

// Round 7
// 1303.934 us; speedup vs baseline: 1.1121x; 1.1121x over previous
//
#include <hip/hip_runtime.h>
#include <math.h>

typedef unsigned short u16;
typedef u16 u16x8 __attribute__((ext_vector_type(8)));
typedef __bf16 bf16x8 __attribute__((ext_vector_type(8)));
typedef float f32x4 __attribute__((ext_vector_type(4)));

#define MBL (1LL << 20)

__device__ __forceinline__ u16 f2bf(float x) {
    unsigned u = __float_as_uint(x);
    return (u16)((u + 0x7fffu + ((u >> 16) & 1u)) >> 16);
}
__device__ __forceinline__ float bf2f(u16 h) { return __uint_as_float(((unsigned)h) << 16); }
__device__ __forceinline__ float silu_f(float x) { return x / (1.f + __expf(-x)); }

#define GLDS(gp, off) __builtin_amdgcn_global_load_lds( \
    (const __attribute__((address_space(1))) void*)(gp), \
    (__attribute__((address_space(3))) void*)(&SL[off]), 16, 0, 0)

// ---------------------------------------------------------------------------
// Split-bf16 MFMA GEMM with XOR-swizzled LDS (physical k8 = logical k8 ^
// ((row>>1)&3)).  GLDS keeps linear dest + pre-swizzled global source
// (rule #21); reads apply the same XOR.  C = (A @ B^T), 3 MFMA/K-slice.
// SPLITA=1: A pre-split (GLDS); SPLITA=0: A fp32, in-reg split + swizzled
// ds_write.  EPI: 0 fp32 store (c*alpha+bias[+addp]); 1 split store (c+bias);
// 2 silu split store; 3 exp(c*alpha) split store + rowsum atomics;
// 4 c/rsum[row] split store.
// z decode: zb = z>>zshift, zh = (z & ((1<<zshift)-1)) + hbase.
// ---------------------------------------------------------------------------
template<int SPLITA, int EPI>
__global__ __launch_bounds__(256)
void gemm_ss(const float* __restrict__ Af,
             const u16* __restrict__ Ah, const u16* __restrict__ Al,
             const u16* __restrict__ Bh, const u16* __restrict__ Bl,
             float* __restrict__ Cf, u16* __restrict__ Ch, u16* __restrict__ Cl,
             float* __restrict__ rsum,
             long lda, long ldb, long ldc, int K, float alpha,
             const float* __restrict__ bias,
             const float* __restrict__ addp, long ldadd,
             int zshift, int hbase, long rstride,
             long sAb, long sAh2, long sBb, long sBh2, long sCb, long sCh2)
{
    const int z = blockIdx.z;
    const int zb = z >> zshift;
    const int zh = (z & ((1 << zshift) - 1)) + hbase;
    const long offA = (long)zb * sAb + (long)zh * sAh2;
    const long offB = (long)zb * sBb + (long)zh * sBh2;
    const long offC = (long)zb * sCb + (long)zh * sCh2;
    if (SPLITA) { Ah += offA; Al += offA; } else { Af += offA; }
    Bh += offB; Bl += offB;
    if (EPI == 0) Cf += offC; else { Ch += offC; Cl += offC; }
    if (EPI >= 3) rsum += (long)z * rstride;

    // LDS: 4 tiles [128 rows][4 k8-chunks of 8 u16]: AH, AL, BH, BL
    __shared__ u16 SL[16384];
    const int AH = 0, AL = 4096, BH = 8192, BL = 12288;

    const int tid = threadIdx.x;
    const int wave = tid >> 6, lane = tid & 63;
    const long m0 = (long)blockIdx.y * 128;
    const long n0 = (long)blockIdx.x * 128;

    // ---- GLDS staging: physical row = wave*16 + t*64 + (lane>>2),
    //      physical k8 = lane&3; source k8 = (lane&3) ^ ((row>>1)&3)
    //      (f(row+64)==f(row), so one swizzled k8 per lane).
    const int prow = (wave << 4) + (lane >> 2);
    const int k8s  = ((lane & 3) ^ ((prow >> 1) & 3)) << 3;
    const long aoff0 = (m0 + prow) * lda + k8s;
    const long aoff1 = (m0 + prow + 64) * lda + k8s;
    const long boff0 = (n0 + prow) * ldb + k8s;
    const long boff1 = (n0 + prow + 64) * ldb + k8s;
    const int ldsW = wave << 9;   // wave*512 u16

    // ---- fp32-A staging map (SPLITA=0): row = tid>>1, k8 pair (tid&1)
    const int srow = tid >> 1;
    const float* gA = SPLITA ? nullptr : (Af + (m0 + srow) * lda + ((tid & 1) << 4));
    const int fs   = (srow >> 1) & 3;
    const int sA0  = srow * 32 + (((((tid & 1) << 1) + 0) ^ fs) << 3);
    const int sA1  = srow * 32 + (((((tid & 1) << 1) + 1) ^ fs) << 3);

    // ---- fragment geometry: quadrant rows are x16 so f(row) = (fr>>1)&3
    const int wr = (wave >> 1) << 6;
    const int wc = (wave & 1) << 6;
    const int fr = lane & 15;
    const int kph = (((lane >> 4) ^ ((fr >> 1) & 3)) << 3);

    f32x4 acc[4][4];
#pragma unroll
    for (int i = 0; i < 4; ++i)
#pragma unroll
        for (int j = 0; j < 4; ++j) acc[i][j] = (f32x4)0.f;

    for (int kb = 0; kb < K; kb += 32) {
        float a[16];
        if (!SPLITA) {
            *(float4*)&a[0]  = *(const float4*)(gA + kb);
            *(float4*)&a[4]  = *(const float4*)(gA + kb + 4);
            *(float4*)&a[8]  = *(const float4*)(gA + kb + 8);
            *(float4*)&a[12] = *(const float4*)(gA + kb + 12);
        }
        __syncthreads();   // previous iteration's LDS reads complete
        GLDS(Bh + boff0 + kb, BH + ldsW);
        GLDS(Bh + boff1 + kb, BH + ldsW + 2048);
        GLDS(Bl + boff0 + kb, BL + ldsW);
        GLDS(Bl + boff1 + kb, BL + ldsW + 2048);
        if (SPLITA) {
            GLDS(Ah + aoff0 + kb, AH + ldsW);
            GLDS(Ah + aoff1 + kb, AH + ldsW + 2048);
            GLDS(Al + aoff0 + kb, AL + ldsW);
            GLDS(Al + aoff1 + kb, AL + ldsW + 2048);
        } else {
            u16 hv[16], lv[16];
#pragma unroll
            for (int u = 0; u < 16; ++u) {
                u16 h = f2bf(a[u]); hv[u] = h; lv[u] = f2bf(a[u] - bf2f(h));
            }
            *(u16x8*)&SL[AH + sA0] = *(u16x8*)&hv[0];
            *(u16x8*)&SL[AH + sA1] = *(u16x8*)&hv[8];
            *(u16x8*)&SL[AL + sA0] = *(u16x8*)&lv[0];
            *(u16x8*)&SL[AL + sA1] = *(u16x8*)&lv[8];
        }
        __syncthreads();   // drains vmcnt (compiler) + lgkm

        bf16x8 fah[4], fal[4], fbh[4], fbl[4];
#pragma unroll
        for (int i = 0; i < 4; ++i) {
            const int r = (wr + (i << 4) + fr) * 32 + kph;
            fah[i] = *(const bf16x8*)&SL[AH + r];
            fal[i] = *(const bf16x8*)&SL[AL + r];
        }
#pragma unroll
        for (int j = 0; j < 4; ++j) {
            const int r = (wc + (j << 4) + fr) * 32 + kph;
            fbh[j] = *(const bf16x8*)&SL[BH + r];
            fbl[j] = *(const bf16x8*)&SL[BL + r];
        }
#pragma unroll
        for (int i = 0; i < 4; ++i)
#pragma unroll
            for (int j = 0; j < 4; ++j) {
                acc[i][j] = __builtin_amdgcn_mfma_f32_16x16x32_bf16(fah[i], fbh[j], acc[i][j], 0, 0, 0);
                acc[i][j] = __builtin_amdgcn_mfma_f32_16x16x32_bf16(fah[i], fbl[j], acc[i][j], 0, 0, 0);
                acc[i][j] = __builtin_amdgcn_mfma_f32_16x16x32_bf16(fal[i], fbh[j], acc[i][j], 0, 0, 0);
            }
    }

    const int rl = (lane >> 4) << 2;
#pragma unroll
    for (int i = 0; i < 4; ++i) {
#pragma unroll
        for (int r2 = 0; r2 < 4; ++r2) {
            const long row = m0 + wr + (i << 4) + rl + r2;
            float psum = 0.f;
            float rinv = 0.f;
            if (EPI == 4) rinv = 1.f / rsum[row];
#pragma unroll
            for (int j = 0; j < 4; ++j) {
                const long col = n0 + wc + (j << 4) + fr;
                float c = acc[i][j][r2];
                if (EPI == 0 || EPI == 1 || EPI == 2) {
                    c = c * alpha + (bias ? bias[col] : 0.f);
                }
                if (EPI == 0) {
                    if (addp) c += addp[row * ldadd + col];
                    Cf[row * ldc + col] = c;
                } else if (EPI == 1 || EPI == 2) {
                    if (EPI == 2) c = silu_f(c);
                    u16 h = f2bf(c);
                    Ch[row * ldc + col] = h;
                    Cl[row * ldc + col] = f2bf(c - bf2f(h));
                } else if (EPI == 3) {
                    float p = __expf(c * alpha);
                    psum += p;
                    u16 h = f2bf(p);
                    Ch[row * ldc + col] = h;
                    Cl[row * ldc + col] = f2bf(p - bf2f(h));
                } else {   // EPI == 4
                    c *= rinv;
                    u16 h = f2bf(c);
                    Ch[row * ldc + col] = h;
                    Cl[row * ldc + col] = f2bf(c - bf2f(h));
                }
            }
            if (EPI == 3) {
                psum += __shfl_xor(psum, 1);
                psum += __shfl_xor(psum, 2);
                psum += __shfl_xor(psum, 4);
                psum += __shfl_xor(psum, 8);
                if ((lane & 15) == 0) atomicAdd(&rsum[row], psum);
            }
        }
    }
}

// elementwise split: fp32 -> bf16 hi + lo.  2048 elems per block.
__global__ __launch_bounds__(256)
void split_f32(const float* __restrict__ in, u16* __restrict__ hi, u16* __restrict__ lo)
{
    const long i = (((long)blockIdx.x << 8) + threadIdx.x) << 3;
    float4 v0 = *(const float4*)(in + i), v1 = *(const float4*)(in + i + 4);
    float f[8] = {v0.x, v0.y, v0.z, v0.w, v1.x, v1.y, v1.z, v1.w};
    u16x8 h8, l8;
#pragma unroll
    for (int u = 0; u < 8; ++u) { u16 h = f2bf(f[u]); h8[u] = h; l8[u] = f2bf(f[u] - bf2f(h)); }
    *(u16x8*)(hi + i) = h8;
    *(u16x8*)(lo + i) = l8;
}

// concat bq|bk|bv -> bqkv[3072]
__global__ __launch_bounds__(256)
void concat_b(const float* __restrict__ a, const float* __restrict__ b,
              const float* __restrict__ c, float* __restrict__ d)
{
    const int i = blockIdx.x * 256 + threadIdx.x;
    d[i] = i < 1024 ? a[i] : (i < 2048 ? b[i - 1024] : c[i - 2048]);
}

// split v slice of qkv [2048][3072] -> vt split [512 d][2048 s] per (batch,head)
__global__ __launch_bounds__(256)
void transpose_vs(const u16* __restrict__ vh, const u16* __restrict__ vl,
                  u16* __restrict__ th, u16* __restrict__ tl,
                  long sVb, long sVh, long sTb, long sTh)
{
    const int z = blockIdx.z, zb = z >> 1, zh = z & 1;
    const u16* sh_ = vh + (long)zb * sVb + (long)zh * sVh;
    const u16* sl_ = vl + (long)zb * sVb + (long)zh * sVh;
    u16* dh = th + (long)zb * sTb + (long)zh * sTh;
    u16* dl = tl + (long)zb * sTb + (long)zh * sTh;
    __shared__ u16 Th[64][72], Tl[64][72];
    const int t = threadIdx.x;
    const int r0 = t >> 3;            // 0..31
    const int c8 = (t & 7) << 3;      // 0..56
    const long sBase = (long)blockIdx.x * 64;   // s
    const long dBase = (long)blockIdx.y * 64;   // d
#pragma unroll
    for (int rr = 0; rr < 64; rr += 32) {
        const long so = (sBase + r0 + rr) * 3072 + dBase + c8;
        *(u16x8*)&Th[r0 + rr][c8] = *(const u16x8*)(sh_ + so);
        *(u16x8*)&Tl[r0 + rr][c8] = *(const u16x8*)(sl_ + so);
    }
    __syncthreads();
#pragma unroll
    for (int rr = 0; rr < 64; rr += 32) {
        const int dr = r0 + rr;
        u16x8 oh, ol;
#pragma unroll
        for (int u = 0; u < 8; ++u) { oh[u] = Th[c8 + u][dr]; ol[u] = Tl[c8 + u][dr]; }
        const long dofs = (dBase + dr) * 2048 + sBase + c8;
        *(u16x8*)&dh[dofs] = oh;
        *(u16x8*)&dl[dofs] = ol;
    }
}

// LayerNorm rows of 512; 1 wave/row, 4 rows/block
__global__ __launch_bounds__(256)
void layernorm_rows(const float* __restrict__ h,
                    const float* __restrict__ gamma,
                    const float* __restrict__ beta,
                    float* __restrict__ o)
{
    const int lane = threadIdx.x & 63;
    const long row = ((long)blockIdx.x << 2) + (threadIdx.x >> 6);
    const float* hr = h + row * 512;
    float v[8];
    *(float4*)&v[0] = *(const float4*)(hr + (lane << 3));
    *(float4*)&v[4] = *(const float4*)(hr + (lane << 3) + 4);
    float s = 0.f;
#pragma unroll
    for (int i = 0; i < 8; ++i) s += v[i];
#pragma unroll
    for (int off = 32; off >= 1; off >>= 1) s += __shfl_xor(s, off);
    const float mu = s * (1.f / 512.f);
    float sq = 0.f;
#pragma unroll
    for (int i = 0; i < 8; ++i) { v[i] -= mu; sq = fmaf(v[i], v[i], sq); }
#pragma unroll
    for (int off = 32; off >= 1; off >>= 1) sq += __shfl_xor(sq, off);
    const float rs = rsqrtf(sq * (1.f / 512.f) + 1e-5f);
    float g[8], b[8];
    *(float4*)&g[0] = *(const float4*)(gamma + (lane << 3));
    *(float4*)&g[4] = *(const float4*)(gamma + (lane << 3) + 4);
    *(float4*)&b[0] = *(const float4*)(beta + (lane << 3));
    *(float4*)&b[4] = *(const float4*)(beta + (lane << 3) + 4);
    float ov[8];
#pragma unroll
    for (int i = 0; i < 8; ++i) ov[i] = fmaf(v[i] * rs, g[i], b[i]);
    float* orow = o + row * 512;
    *(float4*)(orow + (lane << 3))     = *(float4*)&ov[0];
    *(float4*)(orow + (lane << 3) + 4) = *(float4*)&ov[4];
}

extern "C" void kernel_launch(void* const* d_in, const int* in_sizes, int n_in,
                              void* d_out, int out_size, void* d_ws, size_t ws_size,
                              hipStream_t stream)
{
    const float* x    = (const float*)d_in[0];
    const float* skip = (const float*)d_in[1];
    const float* Wq   = (const float*)d_in[2];
    const float* bq   = (const float*)d_in[3];
    const float* Wk   = (const float*)d_in[4];
    const float* bk   = (const float*)d_in[5];
    const float* Wv   = (const float*)d_in[6];
    const float* bv   = (const float*)d_in[7];
    const float* Wo   = (const float*)d_in[8];
    const float* bo   = (const float*)d_in[9];
    const float* Wl   = (const float*)d_in[10];
    const float* bl   = (const float*)d_in[11];
    const float* gm   = (const float*)d_in[12];
    const float* bt   = (const float*)d_in[13];
    const float* Wp   = (const float*)d_in[14];
    const float* bp   = (const float*)d_in[15];
    float* out = (float*)d_out;

    char* W = (char*)d_ws;
    // ---- fixed region (0..108 MB) ----
    u16* wqkvh = (u16*)(W);                  // [3072][512] hi  (3 MB)
    u16* wqkvl = (u16*)(W + 3 * MBL);
    u16* woh   = (u16*)(W + 6 * MBL);        // [512][1024]
    u16* wol   = (u16*)(W + 7 * MBL);
    u16* wlh   = (u16*)(W + 8 * MBL);        // [512][512]
    u16* wll   = (u16*)(W + 8 * MBL + 512 * 1024);
    u16* wph   = (u16*)(W + 9 * MBL);
    u16* wpl   = (u16*)(W + 9 * MBL + 512 * 1024);
    float* bqkv = (float*)(W + 10 * MBL);    // 3072 f
    float* rsum = (float*)(W + 10 * MBL + 65536);  // 16*2048 f
    u16* ahi  = (u16*)(W + 12 * MBL);        // attO hi [16384][1024] (32 MB)
    u16* alo  = (u16*)(W + 44 * MBL);
    u16* ophi = (u16*)(W + 76 * MBL);        // oproj hi [16384][512] (16 MB)
    u16* oplo = (u16*)(W + 92 * MBL);
    float* hb  = (float*)(W + 12 * MBL);     // overlays attO-hi (dead after Wo)
    float* lnh = (float*)(W + 44 * MBL);     // overlays attO-lo
    char* SLOTS = W + 108 * MBL;

    // ---- adaptive grouping ----
    long avail = (long)ws_size - 108 * MBL;
    int gb; bool hseq;
    if (avail >= 64 * MBL) {
        hseq = false;
        long g = avail / (64 * MBL);
        gb = (int)(g > 8 ? 8 : g);
    } else {
        hseq = true; gb = 1;                 // needs >= 48 MB avail
    }
    const long SLOT_B = hseq ? 48 * MBL : 64 * MBL;
    const long SLOT_U = SLOT_B >> 1;         // u16 stride
    // in-slot offsets (u16): qkv_h 0, qkv_l 12MB, vt 24MB, P 32MB
    u16* qkvh0 = (u16*)(SLOTS);
    u16* qkvl0 = (u16*)(SLOTS + 12 * MBL);
    u16* vth0  = (u16*)(SLOTS + 24 * MBL);
    u16* ph0   = (u16*)(SLOTS + 32 * MBL);

    const float sscale = 0.044194173824159216f;   // 1/sqrt(512)
    const long Z = 0;

    hipMemsetAsync(rsum, 0, 16 * 2048 * 4, stream);

    split_f32<<<256, 256, 0, stream>>>(Wq, wqkvh, wqkvl);
    split_f32<<<256, 256, 0, stream>>>(Wk, wqkvh + 524288, wqkvl + 524288);
    split_f32<<<256, 256, 0, stream>>>(Wv, wqkvh + 1048576, wqkvl + 1048576);
    split_f32<<<256, 256, 0, stream>>>(Wo, woh, wol);
    split_f32<<<128, 256, 0, stream>>>(Wl, wlh, wll);
    split_f32<<<128, 256, 0, stream>>>(Wp, wph, wpl);
    concat_b<<<12, 256, 0, stream>>>(bq, bk, bv, bqkv);

    for (int b0 = 0; b0 < 8; b0 += gb) {
        const int gc = (8 - b0) < gb ? (8 - b0) : gb;
        // ---- merged QKV: [gc*2048,512] @ Wqkv[3072,512]^T -> split, ldc 3072
        gemm_ss<0, 1><<<dim3(24, 16, gc), 256, 0, stream>>>(
            x + (long)b0 * 1048576, nullptr, nullptr, wqkvh, wqkvl,
            nullptr, qkvh0, qkvl0, nullptr,
            512, 512, 3072, 512, 1.f, bqkv, nullptr, 0,
            0, 0, 0,
            1048576L, Z, Z, Z, SLOT_U, Z);
        // ---- v slice -> vt split
        transpose_vs<<<dim3(32, 8, 2 * gc), 256, 0, stream>>>(
            qkvh0 + 2048, qkvl0 + 2048, vth0, vth0 + 1048576,
            SLOT_U, 512, SLOT_U, 2097152L);
        if (!hseq) {
            // ---- P~ = exp(q@k^T/sqrt(512)) + rowsums
            gemm_ss<1, 3><<<dim3(16, 16, 2 * gc), 256, 0, stream>>>(
                nullptr, qkvh0, qkvl0, qkvh0 + 1024, qkvl0 + 1024,
                nullptr, ph0, ph0 + 2048, rsum + (long)b0 * 4096,
                3072, 3072, 4096, 512, sscale, nullptr, nullptr, 0,
                1, 0, 2048,
                SLOT_U, 512, SLOT_U, 512, SLOT_U, 8388608L);
            // ---- attO = (P~ @ vt^T) / rowsum
            gemm_ss<1, 4><<<dim3(4, 16, 2 * gc), 256, 0, stream>>>(
                nullptr, ph0, ph0 + 2048, vth0, vth0 + 1048576,
                nullptr, ahi + (long)b0 * 2097152, alo + (long)b0 * 2097152,
                rsum + (long)b0 * 4096,
                4096, 2048, 1024, 2048, 1.f, nullptr, nullptr, 0,
                1, 0, 2048,
                SLOT_U, 8388608L, SLOT_U, 2097152L, 2097152L, 512);
        } else {
            for (int h = 0; h < 2; ++h) {
                gemm_ss<1, 3><<<dim3(16, 16, gc), 256, 0, stream>>>(
                    nullptr, qkvh0, qkvl0, qkvh0 + 1024, qkvl0 + 1024,
                    nullptr, ph0, ph0 + 2048, rsum + ((long)b0 * 2 + h) * 2048,
                    3072, 3072, 4096, 512, sscale, nullptr, nullptr, 0,
                    0, h, 4096,
                    SLOT_U, 512, SLOT_U, 512, SLOT_U, Z);
                gemm_ss<1, 4><<<dim3(4, 16, gc), 256, 0, stream>>>(
                    nullptr, ph0, ph0 + 2048, vth0, vth0 + 1048576,
                    nullptr, ahi + (long)b0 * 2097152, alo + (long)b0 * 2097152,
                    rsum + ((long)b0 * 2 + h) * 2048,
                    4096, 2048, 1024, 2048, 1.f, nullptr, nullptr, 0,
                    0, h, 4096,
                    SLOT_U, Z, SLOT_U, 2097152L, 2097152L, 512);
            }
        }
    }

    // ---- oproj = silu(attO @ Wo^T + bo), split ----
    gemm_ss<1, 2><<<dim3(4, 128, 1), 256, 0, stream>>>(
        nullptr, ahi, alo, woh, wol, nullptr, ophi, oplo, nullptr,
        1024, 1024, 512, 1024, 1.f, bo, nullptr, 0,
        0, 0, 0, Z, Z, Z, Z, Z, Z);
    // ---- hb = oproj @ Wl^T + bl (fp32) ----
    gemm_ss<1, 0><<<dim3(4, 128, 1), 256, 0, stream>>>(
        nullptr, ophi, oplo, wlh, wll, hb, nullptr, nullptr, nullptr,
        512, 512, 512, 512, 1.f, bl, nullptr, 0,
        0, 0, 0, Z, Z, Z, Z, Z, Z);
    // ---- LayerNorm ----
    layernorm_rows<<<4096, 256, 0, stream>>>(hb, gm, bt, lnh);
    // ---- out = lnh + skip @ Wp^T + bp ----
    gemm_ss<0, 0><<<dim3(4, 128, 1), 256, 0, stream>>>(
        skip, nullptr, nullptr, wph, wpl, out, nullptr, nullptr, nullptr,
        512, 512, 512, 512, 1.f, bp, lnh, 512,
        0, 0, 0, Z, Z, Z, Z, Z, Z);
}